// Round 7
// baseline (173.431 us; speedup 1.0000x reference)
//
#include <hip/hip_runtime.h>

typedef unsigned short u16;
typedef unsigned long long u64;
typedef float floatx4 __attribute__((ext_vector_type(4)));
typedef short shortx8 __attribute__((ext_vector_type(8)));

__device__ inline u16 f2bf(float f) {
  unsigned u = __float_as_uint(f);
  u += 0x7fffu + ((u >> 16) & 1u);
  return (u16)(u >> 16);
}

// async global->LDS, 16B per lane (wave-uniform LDS base + lane*16).
__device__ __forceinline__ void gl16(const u16* g, const u16* l) {
  __builtin_amdgcn_global_load_lds(
      (const __attribute__((address_space(1))) unsigned int*)(u64)(const void*)g,
      (__attribute__((address_space(3))) unsigned int*)(unsigned)(u64)(const void*)l,
      16, 0, 0);
}

// ---------------------------------------------------------------------------
// fp32 -> bf16 conversion (full: q/v + weights)
// ushort offsets: qb 0 | vb 4194304 | w1cat 8388608 | w3cat 8912896 |
// wob 9437184 | w2b0p 9699328 (128x512) | w2b1p 9764864 (256x512) | end 9895936
// ---------------------------------------------------------------------------
__global__ __launch_bounds__(256) void convert_all(
    const float* __restrict__ q, const float* __restrict__ v,
    const float* __restrict__ w10, const float* __restrict__ w11,
    const float* __restrict__ w30, const float* __restrict__ w31,
    const float* __restrict__ wo, const float* __restrict__ w20,
    const float* __restrict__ w21, u16* __restrict__ base) {
  size_t e = ((size_t)blockIdx.x * 256 + threadIdx.x) * 4;
  const float* src;
  u16* dst;
  size_t le;
  unsigned prows;
  if (e < 4194304ull)      { src = q;   dst = base;            le = e;            prows = 0x7fffffffu; }
  else if (e < 8388608ull) { src = v;   dst = base + 4194304;  le = e - 4194304;  prows = 0x7fffffffu; }
  else if (e < 8650752ull) { src = w10; dst = base + 8388608;  le = e - 8388608;  prows = 0x7fffffffu; }
  else if (e < 8912896ull) { src = w11; dst = base + 8650752;  le = e - 8650752;  prows = 0x7fffffffu; }
  else if (e < 9175040ull) { src = w30; dst = base + 8912896;  le = e - 8912896;  prows = 0x7fffffffu; }
  else if (e < 9437184ull) { src = w31; dst = base + 9175040;  le = e - 9175040;  prows = 0x7fffffffu; }
  else if (e < 9699328ull) { src = wo;  dst = base + 9437184;  le = e - 9437184;  prows = 0x7fffffffu; }
  else if (e < 9764864ull) { src = w20; dst = base + 9699328;  le = e - 9699328;  prows = 124; }
  else                     { src = w21; dst = base + 9764864;  le = e - 9764864;  prows = 244; }
  float4 val = make_float4(0.f, 0.f, 0.f, 0.f);
  if ((unsigned)(le >> 9) < prows) val = *(const float4*)(src + le);
  unsigned p0 = (unsigned)f2bf(val.x) | ((unsigned)f2bf(val.y) << 16);
  unsigned p1 = (unsigned)f2bf(val.z) | ((unsigned)f2bf(val.w) << 16);
  *(uint2*)(dst + le) = make_uint2(p0, p1);
}

// ---------------------------------------------------------------------------
// m97-structure GEMM core (kept for k_logits / k_final)
// ---------------------------------------------------------------------------
template <int OUTBF>
__device__ __forceinline__ void gemm_core(
    const u16* __restrict__ A, int lda, const u16* __restrict__ W, int ldw,
    float* __restrict__ Cf, u16* __restrict__ Cb, int ldc, int relu,
    u16* lA, u16* lB) {
  const int tid = threadIdx.x;
  const int wave = tid >> 6, lane = tid & 63;
  const int wm = (wave >> 1) * 64, wn = (wave & 1) * 64;
  const int lr = lane & 15, kq = (lane >> 4) * 8;
  const int sr = lane >> 2, sc = (lane & 3) * 8;

  floatx4 acc[4][4];
#pragma unroll
  for (int i = 0; i < 4; ++i)
#pragma unroll
    for (int j = 0; j < 4; ++j) acc[i][j] = (floatx4){0.f, 0.f, 0.f, 0.f};

  const u16* ga0 = A + (u64)(wave * 32 + sr) * lda + sc;
  const u16* ga1 = A + (u64)(wave * 32 + 16 + sr) * lda + sc;
  const u16* gb0 = W + (u64)(wave * 32 + sr) * ldw + sc;
  const u16* gb1 = W + (u64)(wave * 32 + 16 + sr) * ldw + sc;
  u16* la0 = lA + (wave * 32) * 32;
  u16* la1 = lA + (wave * 32 + 16) * 32;
  u16* lb0 = lB + (wave * 32) * 32;
  u16* lb1 = lB + (wave * 32 + 16) * 32;

  for (int k0 = 0; k0 < 512; k0 += 32) {
    __syncthreads();
    gl16(ga0 + k0, la0);
    gl16(ga1 + k0, la1);
    gl16(gb0 + k0, lb0);
    gl16(gb1 + k0, lb1);
    __syncthreads();
    shortx8 af[4], bf8[4];
#pragma unroll
    for (int i = 0; i < 4; ++i) {
      af[i] = *(const shortx8*)&lA[(wm + i * 16 + lr) * 32 + kq];
      bf8[i] = *(const shortx8*)&lB[(wn + i * 16 + lr) * 32 + kq];
    }
#pragma unroll
    for (int mi = 0; mi < 4; ++mi)
#pragma unroll
      for (int ni = 0; ni < 4; ++ni)
        acc[mi][ni] = __builtin_amdgcn_mfma_f32_16x16x32_bf16(af[mi], bf8[ni], acc[mi][ni], 0, 0, 0);
  }
  const int er = wm + (lane >> 4) * 4;
  const int ec = wn + lr;
#pragma unroll
  for (int mi = 0; mi < 4; ++mi)
#pragma unroll
    for (int ni = 0; ni < 4; ++ni)
#pragma unroll
      for (int r = 0; r < 4; ++r) {
        float vv = acc[mi][ni][r];
        if (relu) vv = fmaxf(vv, 0.f);
        u64 off = (u64)(er + mi * 16 + r) * (u64)ldc + (u64)(ec + ni * 16);
        if (OUTBF) Cb[off] = f2bf(vv);
        else Cf[off] = vv;
      }
}

// ---------------------------------------------------------------------------
// k_qv9 (round-7): TRAFFIC-optimal q/v projection replacing the 256^2 8-phase
// design. Bookkeeping across rounds showed k_qv is MEMORY-bound, not
// compute-bound: R0's (128,8)-grid version sat exactly at its 176 MB HBM
// floor (8x A re-read), and the 256^2 rewrite only reached ~25 us because
// 1 block/CU + 128-VGPR-cap made it fragile. This design:
//   tile 128(M) x 256(N), BK=32, 8 waves (2M x 4N), 512 thr
//   acc[4][4] = 64 VGPR -> total live ~110 <= the RA's 128 cap (pinned via
//   __launch_bounds__(512,4)); no spill by construction.
//   LDS 24 KB single-buffered (m97 2-barrier loop) -> 2 blocks/CU resident
//   (16 waves x 128 VGPR = full file) -> cross-block overlap hides barriers.
//   grid 512, bijective XCD swizzle: XCD x gets 64 consecutive tiles =
//   16 A-panels (2 MB) + 4 B-panels (1 MB) < 4 MB L2 -> A re-read (4x) is
//   L2-hit -> HBM ~= A 16.8 + B 2 + C 33.6 = 52 MB -> 8.3 us floor.
// K loop sequential in steps of 32 -> accumulation order per element
// identical to all prior rounds (absmax tripwire 0.0004882812).
// ---------------------------------------------------------------------------
__global__ __launch_bounds__(512, 4) void k_qv9(
    const u16* __restrict__ qb, const u16* __restrict__ vb,
    const u16* __restrict__ w1, const u16* __restrict__ w3,
    u16* __restrict__ rq, u16* __restrict__ vc) {
  __shared__ __align__(16) u16 lA[128 * 32];
  __shared__ __align__(16) u16 lB[256 * 32];
  const int bid = blockIdx.x;
  const int lb = (bid & 7) * 64 + (bid >> 3);  // XCD swizzle, 512%8==0 bijective
  const bool isq = lb < 256;
  const int lq = lb & 255;
  const int m0 = (lq >> 2) * 128;   // 64 m-panels
  const int n0 = (lq & 3) * 256;    // 4 n-tiles
  const u16* __restrict__ A = isq ? qb : vb;   // [8192][512]
  const u16* __restrict__ W = isq ? w1 : w3;   // [1024][512]
  u16* __restrict__ C = isq ? rq : vc;         // [8192][1024]

  const int tid = threadIdx.x;
  const int wv = tid >> 6, lane = tid & 63;
  const int wm = (wv >> 2) * 64;    // 0 / 64
  const int wn = (wv & 3) * 64;     // 0..192
  const int lr = lane & 15, kq = (lane >> 4) * 8;
  const int sr = lane >> 2, sc = (lane & 3) * 8;

  floatx4 acc[4][4];
#pragma unroll
  for (int i = 0; i < 4; ++i)
#pragma unroll
    for (int j = 0; j < 4; ++j) acc[i][j] = (floatx4){0.f, 0.f, 0.f, 0.f};

  // staging addresses (m97 pattern, generalized to 8 waves):
  // A: wave wv stages rows wv*16 .. wv*16+15 (1 gl16/thread)
  // B: wave wv stages rows wv*32 .. wv*32+31 (2 gl16/thread)
  const u16* ga0 = A + (u64)(m0 + wv * 16 + sr) * 512 + sc;
  const u16* gb0 = W + (u64)(n0 + wv * 32 + sr) * 512 + sc;
  const u16* gb1 = W + (u64)(n0 + wv * 32 + 16 + sr) * 512 + sc;
  u16* la0 = lA + (wv * 16) * 32;
  u16* lb0 = lB + (wv * 32) * 32;
  u16* lb1 = lB + (wv * 32 + 16) * 32;

  for (int k0 = 0; k0 < 512; k0 += 32) {
    __syncthreads();
    gl16(ga0 + k0, la0);
    gl16(gb0 + k0, lb0);
    gl16(gb1 + k0, lb1);
    __syncthreads();
    shortx8 af[4], bf8[4];
#pragma unroll
    for (int i = 0; i < 4; ++i) {
      af[i] = *(const shortx8*)&lA[(wm + i * 16 + lr) * 32 + kq];
      bf8[i] = *(const shortx8*)&lB[(wn + i * 16 + lr) * 32 + kq];
    }
#pragma unroll
    for (int mi = 0; mi < 4; ++mi)
#pragma unroll
      for (int ni = 0; ni < 4; ++ni)
        acc[mi][ni] = __builtin_amdgcn_mfma_f32_16x16x32_bf16(af[mi], bf8[ni], acc[mi][ni], 0, 0, 0);
  }

  const int er = m0 + wm + (lane >> 4) * 4;
  const int ec = n0 + wn + lr;
#pragma unroll
  for (int mi = 0; mi < 4; ++mi)
#pragma unroll
    for (int ni = 0; ni < 4; ++ni)
#pragma unroll
      for (int r = 0; r < 4; ++r) {
        float vv = acc[mi][ni][r];
        if (isq) vv = fmaxf(vv, 0.f);
        C[(u64)(er + mi * 16 + r) * 1024 + (u64)(ec + ni * 16)] = f2bf(vv);
      }
}

// fused logits for both scales: grid (64, 3).
__global__ __launch_bounds__(256, 2) void k_logits(
    const u16* __restrict__ rq, const u16* __restrict__ w20,
    const u16* __restrict__ w21, float* __restrict__ lg) {
  __shared__ __align__(16) u16 lA[128 * 32];
  __shared__ __align__(16) u16 lB[128 * 32];
  const int am = blockIdx.x * 128;
  const int y = blockIdx.y;
  const u16* A = rq + (u64)am * 1024 + (y == 0 ? 0 : 512);
  const u16* W = (y == 0) ? w20 : (w21 + (u64)(y - 1) * 128 * 512);
  float* Cf = lg + (u64)am * 384 + y * 128;
  gemm_core<0>(A, 1024, W, 512, Cf, nullptr, 384, 0, lA, lB);
}

// final projection: grid (64, 4), fp32 out.
__global__ __launch_bounds__(256, 2) void k_final(
    const u16* __restrict__ xb, const u16* __restrict__ wo,
    float* __restrict__ out) {
  __shared__ __align__(16) u16 lA[128 * 32];
  __shared__ __align__(16) u16 lB[128 * 32];
  const int am = blockIdx.x * 128, bn = blockIdx.y * 128;
  gemm_core<0>(xb + (u64)am * 512, 512, wo + (u64)bn * 512, 512,
               out + (u64)am * 512 + bn, nullptr, 512, 0, lA, lB);
}

// ---------------------------------------------------------------------------
// MFMA attention (verbatim, round-9 d-SPLIT version)
// ---------------------------------------------------------------------------
#define VLDT 136
#define ESL 152

template <int CS, int CHUNK>
__device__ __forceinline__ void attn_mfma_pass(
    const float* __restrict__ lg,   // pre-offset to scale+head col base, row stride 384
    const u16* __restrict__ vbh,    // vcat + scale*512 + h*128 + dh*64, row stride 1024
    int bb, int t0, float swv,
    u16* vT, u16* es16, float* invsum, floatx4 (&o)[4]) {
  constexpr int HALF = (CS - 1) / 2;
  constexpr int NW = 64 + CS - 1;  // valid window rows (94 / 124)
  const int tid = threadIdx.x;
  const int wave = tid >> 6, lane = tid & 63;
  const int lr = lane & 15, kq = (lane >> 4) * 8;

  __syncthreads();  // prior consumers done with vT/es16/invsum

  // stage V-window (64 d-cols) transposed+swizzled; coalesced 128B segments.
#pragma unroll
  for (int it = 0; it < 4; ++it) {
    int idx = it * 256 + tid;
    int r = idx >> 3;              // 0..127
    int dl8 = (idx & 7) * 8;       // 0..56 (local d chunk)
    int t = t0 + r - HALF;
    uint4 u = make_uint4(0u, 0u, 0u, 0u);
    if (r < NW && t >= 0 && t < 2048)
      u = *(const uint4*)&vbh[(u64)(bb + t) * 1024 + dl8];
    int sb = (((r >> 3) ^ ((dl8 >> 3) & 7)) << 3) + (r & 7);
    u16* wp = &vT[dl8 * VLDT + sb];
    const u16* us = (const u16*)&u;
#pragma unroll
    for (int j = 0; j < 8; ++j) wp[j * VLDT] = us[j];
  }

  // exp (chunked global reads) + complement zeros + quad row-sum via shfl
  {
    int tt = tid >> 2, qq = tid & 3;
    u16* row = es16 + tt * ESL;
    const int lo = tt, hi = tt + CS;
#pragma unroll
    for (int j = 0; j < 32; ++j) {
      int x = qq * 32 + j;
      if (x < lo || x >= hi) row[x] = 0;
    }
    const float* lrow = lg + (u64)(bb + t0 + tt) * 384 + qq * CHUNK;
    float ps = 0.f;
#pragma unroll
    for (int j = 0; j < CHUNK; ++j) {
      int c = qq * CHUNK + j;
      if (c < CS) {
        float ev = __expf(lrow[j]);
        row[lo + c] = f2bf(ev);
        ps += ev;
      }
    }
    ps += __shfl_xor(ps, 1, 64);
    ps += __shfl_xor(ps, 2, 64);
    if (qq == 0) invsum[tt] = swv / ps;
  }
  __syncthreads();

  // MFMA: wave w owns output rows w*16..w*16+15; band limits k-blocks.
  const int kb_lo = (wave * 16) >> 5;
  const int kb_hi = (wave * 16 + 15 + CS - 1) >> 5;
  floatx4 acc[4];
#pragma unroll
  for (int nt = 0; nt < 4; ++nt) acc[nt] = (floatx4){0.f, 0.f, 0.f, 0.f};
  for (int kb = kb_lo; kb <= kb_hi; ++kb) {
    shortx8 af = *(const shortx8*)&es16[(wave * 16 + lr) * ESL + kb * 32 + kq];
    int rb8 = kb * 4 + (lane >> 4);
#pragma unroll
    for (int nt = 0; nt < 4; ++nt) {
      int d_row = nt * 16 + lr;   // 0..63 local d
      int blk = (rb8 ^ ((d_row >> 3) & 7)) << 3;
      shortx8 bf8 = *(const shortx8*)&vT[d_row * VLDT + blk];
      acc[nt] = __builtin_amdgcn_mfma_f32_16x16x32_bf16(af, bf8, acc[nt], 0, 0, 0);
    }
  }
  // fold swv/rowsum, accumulate into persistent o (C-layout rows)
  float invs[4];
#pragma unroll
  for (int rr = 0; rr < 4; ++rr)
    invs[rr] = invsum[wave * 16 + (lane >> 4) * 4 + rr];
#pragma unroll
  for (int nt = 0; nt < 4; ++nt)
#pragma unroll
    for (int rr = 0; rr < 4; ++rr) o[nt][rr] += acc[nt][rr] * invs[rr];
}

__global__ __launch_bounds__(256, 2) void k_attn4(
    const float* __restrict__ lg, const u16* __restrict__ vcat,
    const float* __restrict__ swp, u16* __restrict__ xbw) {
  __shared__ __align__(16) u16 vT[64 * VLDT];
  __shared__ __align__(16) u16 es16[64 * ESL];
  __shared__ float invsum[64];
  const int tid = threadIdx.x;
  const int wave = tid >> 6, lane = tid & 63;
  const int lr = lane & 15;
  const int t0 = blockIdx.x * 64;
  const int h = blockIdx.y >> 1, dh = blockIdx.y & 1;
  const int b = blockIdx.z;
  const int bb = b * 2048;
  const int m0 = bb + t0;

  float a0 = swp[0], a1 = swp[1];
  float mx = fmaxf(a0, a1);
  float e0 = __expf(a0 - mx), e1 = __expf(a1 - mx);
  float inv = 1.f / (e0 + e1);

  floatx4 o[4];
#pragma unroll
  for (int nt = 0; nt < 4; ++nt) o[nt] = (floatx4){0.f, 0.f, 0.f, 0.f};

  attn_mfma_pass<31, 8>(lg + h * 31, vcat + h * 128 + dh * 64,
                        bb, t0, e0 * inv, vT, es16, invsum, o);
  attn_mfma_pass<61, 16>(lg + 128 + h * 61, vcat + 512 + h * 128 + dh * 64,
                         bb, t0, e1 * inv, vT, es16, invsum, o);

  // epilogue: stage bf16 output half-tile in es16 (reuse), coalesced stores
  __syncthreads();
#pragma unroll
  for (int nt = 0; nt < 4; ++nt)
#pragma unroll
    for (int rr = 0; rr < 4; ++rr) {
      int trow = wave * 16 + (lane >> 4) * 4 + rr;
      es16[trow * ESL + nt * 16 + lr] = f2bf(o[nt][rr]);
    }
  __syncthreads();
#pragma unroll
  for (int rep = 0; rep < 2; ++rep) {
    int idx = rep * 256 + tid;
    int trow = idx >> 3;            // 0..63
    int col8 = (idx & 7) * 8;       // 0..56
    uint4 u = *(const uint4*)&es16[trow * ESL + col8];
    *(uint4*)&xbw[(u64)(m0 + trow) * 512 + h * 128 + dh * 64 + col8] = u;
  }
}

// ---------------------------------------------------------------------------
extern "C" void kernel_launch(void* const* d_in, const int* in_sizes, int n_in,
                              void* d_out, int out_size, void* d_ws, size_t ws_size,
                              hipStream_t stream) {
  const float* q   = (const float*)d_in[0];
  const float* v   = (const float*)d_in[2];
  const float* w10 = (const float*)d_in[3];
  const float* w11 = (const float*)d_in[4];
  const float* w20 = (const float*)d_in[5];
  const float* w21 = (const float*)d_in[6];
  const float* w30 = (const float*)d_in[7];
  const float* w31 = (const float*)d_in[8];
  const float* sw  = (const float*)d_in[9];
  const float* wo  = (const float*)d_in[10];
  float* out = (float*)d_out;

  u16* base  = (u16*)d_ws;
  u16* qb    = base;
  u16* vb    = base + 4194304;
  u16* w1cat = base + 8388608;
  u16* w3cat = base + 8912896;
  u16* wob   = base + 9437184;
  u16* w2b0  = base + 9699328;
  u16* w2b1  = base + 9764864;
  char* fb = (char*)d_ws + 19791872;
  float* logitsC = (float*)fb;            // [8192][384]
  u16* rqcat = (u16*)(logitsC + 3145728); // [8192][1024]
  u16* vcat  = rqcat + 8388608;           // [8192][1024]
  u16* xb    = vcat + 8388608;            // [8192][512]
  // total ws use: 74,317,824 bytes

  convert_all<<<dim3(9664), dim3(256), 0, stream>>>(q, v, w10, w11, w30, w31, wo, w20, w21, base);

  dim3 blk(256);
  k_qv9<<<dim3(512), dim3(512), 0, stream>>>(qb, vb, w1cat, w3cat, rqcat, vcat);
  k_logits<<<dim3(64, 3), blk, 0, stream>>>(rqcat, w2b0, w2b1, logitsC);
  k_attn4<<<dim3(32, 8, 4), blk, 0, stream>>>(logitsC, vcat, sw, xb);
  k_final<<<dim3(64, 4), blk, 0, stream>>>(xb, wob, out);
}

// Round 8
// 172.923 us; speedup vs baseline: 1.0029x; 1.0029x over previous
//
#include <hip/hip_runtime.h>

typedef unsigned short u16;
typedef unsigned long long u64;
typedef float floatx4 __attribute__((ext_vector_type(4)));
typedef short shortx8 __attribute__((ext_vector_type(8)));

__device__ inline u16 f2bf(float f) {
  unsigned u = __float_as_uint(f);
  u += 0x7fffu + ((u >> 16) & 1u);
  return (u16)(u >> 16);
}

// async global->LDS, 16B per lane (wave-uniform LDS base + lane*16).
__device__ __forceinline__ void gl16(const u16* g, const u16* l) {
  __builtin_amdgcn_global_load_lds(
      (const __attribute__((address_space(1))) unsigned int*)(u64)(const void*)g,
      (__attribute__((address_space(3))) unsigned int*)(unsigned)(u64)(const void*)l,
      16, 0, 0);
}

// ---------------------------------------------------------------------------
// fp32 -> bf16 conversion (full: q/v + weights)
// ushort offsets: qb 0 | vb 4194304 | w1cat 8388608 | w3cat 8912896 |
// wob 9437184 | w2b0p 9699328 (128x512) | w2b1p 9764864 (256x512) | end 9895936
// ---------------------------------------------------------------------------
__global__ __launch_bounds__(256) void convert_all(
    const float* __restrict__ q, const float* __restrict__ v,
    const float* __restrict__ w10, const float* __restrict__ w11,
    const float* __restrict__ w30, const float* __restrict__ w31,
    const float* __restrict__ wo, const float* __restrict__ w20,
    const float* __restrict__ w21, u16* __restrict__ base) {
  size_t e = ((size_t)blockIdx.x * 256 + threadIdx.x) * 4;
  const float* src;
  u16* dst;
  size_t le;
  unsigned prows;
  if (e < 4194304ull)      { src = q;   dst = base;            le = e;            prows = 0x7fffffffu; }
  else if (e < 8388608ull) { src = v;   dst = base + 4194304;  le = e - 4194304;  prows = 0x7fffffffu; }
  else if (e < 8650752ull) { src = w10; dst = base + 8388608;  le = e - 8388608;  prows = 0x7fffffffu; }
  else if (e < 8912896ull) { src = w11; dst = base + 8650752;  le = e - 8650752;  prows = 0x7fffffffu; }
  else if (e < 9175040ull) { src = w30; dst = base + 8912896;  le = e - 8912896;  prows = 0x7fffffffu; }
  else if (e < 9437184ull) { src = w31; dst = base + 9175040;  le = e - 9175040;  prows = 0x7fffffffu; }
  else if (e < 9699328ull) { src = wo;  dst = base + 9437184;  le = e - 9437184;  prows = 0x7fffffffu; }
  else if (e < 9764864ull) { src = w20; dst = base + 9699328;  le = e - 9699328;  prows = 124; }
  else                     { src = w21; dst = base + 9764864;  le = e - 9764864;  prows = 244; }
  float4 val = make_float4(0.f, 0.f, 0.f, 0.f);
  if ((unsigned)(le >> 9) < prows) val = *(const float4*)(src + le);
  unsigned p0 = (unsigned)f2bf(val.x) | ((unsigned)f2bf(val.y) << 16);
  unsigned p1 = (unsigned)f2bf(val.z) | ((unsigned)f2bf(val.w) << 16);
  *(uint2*)(dst + le) = make_uint2(p0, p1);
}

// ---------------------------------------------------------------------------
// m97-structure GEMM core (kept for k_logits / k_final)
// ---------------------------------------------------------------------------
template <int OUTBF>
__device__ __forceinline__ void gemm_core(
    const u16* __restrict__ A, int lda, const u16* __restrict__ W, int ldw,
    float* __restrict__ Cf, u16* __restrict__ Cb, int ldc, int relu,
    u16* lA, u16* lB) {
  const int tid = threadIdx.x;
  const int wave = tid >> 6, lane = tid & 63;
  const int wm = (wave >> 1) * 64, wn = (wave & 1) * 64;
  const int lr = lane & 15, kq = (lane >> 4) * 8;
  const int sr = lane >> 2, sc = (lane & 3) * 8;

  floatx4 acc[4][4];
#pragma unroll
  for (int i = 0; i < 4; ++i)
#pragma unroll
    for (int j = 0; j < 4; ++j) acc[i][j] = (floatx4){0.f, 0.f, 0.f, 0.f};

  const u16* ga0 = A + (u64)(wave * 32 + sr) * lda + sc;
  const u16* ga1 = A + (u64)(wave * 32 + 16 + sr) * lda + sc;
  const u16* gb0 = W + (u64)(wave * 32 + sr) * ldw + sc;
  const u16* gb1 = W + (u64)(wave * 32 + 16 + sr) * ldw + sc;
  u16* la0 = lA + (wave * 32) * 32;
  u16* la1 = lA + (wave * 32 + 16) * 32;
  u16* lb0 = lB + (wave * 32) * 32;
  u16* lb1 = lB + (wave * 32 + 16) * 32;

  for (int k0 = 0; k0 < 512; k0 += 32) {
    __syncthreads();
    gl16(ga0 + k0, la0);
    gl16(ga1 + k0, la1);
    gl16(gb0 + k0, lb0);
    gl16(gb1 + k0, lb1);
    __syncthreads();
    shortx8 af[4], bf8[4];
#pragma unroll
    for (int i = 0; i < 4; ++i) {
      af[i] = *(const shortx8*)&lA[(wm + i * 16 + lr) * 32 + kq];
      bf8[i] = *(const shortx8*)&lB[(wn + i * 16 + lr) * 32 + kq];
    }
#pragma unroll
    for (int mi = 0; mi < 4; ++mi)
#pragma unroll
      for (int ni = 0; ni < 4; ++ni)
        acc[mi][ni] = __builtin_amdgcn_mfma_f32_16x16x32_bf16(af[mi], bf8[ni], acc[mi][ni], 0, 0, 0);
  }
  const int er = wm + (lane >> 4) * 4;
  const int ec = wn + lr;
#pragma unroll
  for (int mi = 0; mi < 4; ++mi)
#pragma unroll
    for (int ni = 0; ni < 4; ++ni)
#pragma unroll
      for (int r = 0; r < 4; ++r) {
        float vv = acc[mi][ni][r];
        if (relu) vv = fmaxf(vv, 0.f);
        u64 off = (u64)(er + mi * 16 + r) * (u64)ldc + (u64)(ec + ni * 16);
        if (OUTBF) Cb[off] = f2bf(vv);
        else Cf[off] = vv;
      }
}

// ---------------------------------------------------------------------------
// k_qv10 (round-8): 128(M)x256(N) tile, BK=64, 8 waves (2Mx4N), FULL 8-phase
// double-buffered ring with counted vmcnt — the R1/R6 schedule at a register
// footprint that fits the RA's immovable 128-VGPR cap.
//   Evidence: k_qv8 (8-phase, 256^2, SPILLS at the 128 cap) = ~25 us;
//   k_qv9 (no spill, but single-buffered -> serial latency) = ~28.5 us.
//   This fixes both: acc[4][4]=64 VGPR + af/bf 24 + addr ~15 = ~105 <= 128
//   (no spill by construction), pipeline keeps loads in flight across
//   barriers (T3+T4).
// LDS 96 KB static: A units [128x32] 4096 elems (1 gl16/thr) at d*8192 +
// kk*4096; B units [2kk][128 r'][32] 8192 elems (2 gl16/thr) at 16384 +
// d*16384 + nh*8192. Same XOR swizzle e^=((e>>6)&7)<<3, same inverse-
// swizzled global sources. Per-phase stages: odd=A(1 load), even=B(2 loads);
// counted waits become vmcnt(3) at P4/P8 (leaves exactly the 3 newest =
// next half-tile's partials; drains everything the next 4 phases read).
// Unit-lifetime audit: each stage overwrites a buffer >=1 barrier after its
// last reader (P1 tgt d1.kk1 freed @P7(i-1); P2 d1.nh1 @P8(i-1); P3 d0.kk0
// @P2; P4 d0.nh0 @P3; P5 d0.kk1 @P4; P6 d0.nh1 @P4; P7 d1.kk0 @P6; P8
// d1.nh0 @P7). Tail iter stages only kt7 (P1/P2), VM0 at P4.
// K ascending in 32-steps -> accumulation order bit-identical (absmax
// tripwire 0.0004882812). Grid 512 (q 256 + v 256), bijective XCD swizzle.
// ---------------------------------------------------------------------------
__global__ __launch_bounds__(512, 2) void k_qv10(
    const u16* __restrict__ qb, const u16* __restrict__ vb,
    const u16* __restrict__ w1, const u16* __restrict__ w3,
    u16* __restrict__ rq, u16* __restrict__ vc) {
  __shared__ __align__(16) u16 lds[49152];  // 96 KB
  const int bid = blockIdx.x;
  const int lb = (bid & 7) * 64 + (bid >> 3);  // XCD swizzle, 512%8==0 bijective
  const bool isq = lb < 256;
  const int lq = lb & 255;
  const int m0 = (lq >> 2) * 128;   // 64 m-panels
  const int n0 = (lq & 3) * 256;    // 4 n-tiles
  const u16* __restrict__ A = isq ? qb : vb;   // [8192][512]
  const u16* __restrict__ W = isq ? w1 : w3;   // [1024][512]
  u16* __restrict__ C = isq ? rq : vc;         // [8192][1024]

  const int tid = threadIdx.x;
  const int wv = tid >> 6, lane = tid & 63;
  const int lr = lane & 15, kq = lane >> 4;

  // read-address precompute (swizzle mask = f(lr) only)
  const unsigned Ca = ((unsigned)((lr >> 1) & 7)) << 3;
  const unsigned afb = ((unsigned)(((wv >> 2) * 64 + lr) * 32 + kq * 8)) ^ Ca;
  const unsigned bfb = ((unsigned)(((wv & 3) * 32 + lr) * 32 + kq * 8)) ^ Ca;

  // A staging source: unit 4096 elems, 1 gl16/thread. dest u=tid*8 (linear),
  // logical g=swz(u): row=g>>5 (0..127), col=g&31.
  const unsigned uA = (unsigned)tid * 8u;
  const unsigned gA_l = uA ^ (((uA >> 6) & 7u) << 3);
  const unsigned gA = (unsigned)(m0 + (int)(gA_l >> 5)) * 512u + (gA_l & 31u);
  const unsigned wvoA = (unsigned)wv * 512u;

  // B staging source: unit 8192 elems [2kk][128 r'][32], 2 gl16/thread.
  // r' -> global row n0 + (r'>>5)*64 + nh*32 + (r'&31); col kk*32 + k.
  const unsigned u0 = (unsigned)(wv * 1024 + lane * 8);
  const unsigned u1 = u0 + 512;
  const unsigned g0 = u0 ^ (((u0 >> 6) & 7) << 3);
  const unsigned g1 = u1 ^ (((u1 >> 6) & 7) << 3);
  const unsigned rp0 = (g0 >> 5) & 127, rp1 = (g1 >> 5) & 127;
  const unsigned gB0 = (unsigned)(n0 + (int)((rp0 >> 5) * 64 + (rp0 & 31))) * 512u
                       + (g0 >> 12) * 32 + (g0 & 31);
  const unsigned gB1 = (unsigned)(n0 + (int)((rp1 >> 5) * 64 + (rp1 & 31))) * 512u
                       + (g1 >> 12) * 32 + (g1 & 31);
  const unsigned wvoB = (unsigned)wv * 1024u;

#define SA(d, kk, ko) \
  gl16(A + gA + (ko) + (kk) * 32u, lds + (d) * 8192 + (kk) * 4096 + wvoA)
#define SB(d, nh, ko) \
  gl16(W + gB0 + (nh) * 16384u + (ko), lds + 16384 + (d) * 16384 + (nh) * 8192 + wvoB); \
  gl16(W + gB1 + (nh) * 16384u + (ko), lds + 16384 + (d) * 16384 + (nh) * 8192 + wvoB + 512)
#define LOAD_AF(kk, d) \
  _Pragma("unroll") \
  for (int m = 0; m < 4; ++m) \
    af[m] = *(const shortx8*)&lds[(d) * 8192 + (kk) * 4096 + afb + (unsigned)m * 512]
#define LOAD_BF(kk, nh, d) \
  bf0 = *(const shortx8*)&lds[16384 + (d) * 16384 + (nh) * 8192 + (kk) * 4096 + bfb]; \
  bf1 = *(const shortx8*)&lds[16384 + (d) * 16384 + (nh) * 8192 + (kk) * 4096 + bfb + 512]
#define MFMA8(nh) \
  __builtin_amdgcn_s_setprio(1); \
  _Pragma("unroll") \
  for (int m = 0; m < 4; ++m) { \
    acc[m][(nh) * 2]     = __builtin_amdgcn_mfma_f32_16x16x32_bf16(af[m], bf0, acc[m][(nh) * 2], 0, 0, 0); \
    acc[m][(nh) * 2 + 1] = __builtin_amdgcn_mfma_f32_16x16x32_bf16(af[m], bf1, acc[m][(nh) * 2 + 1], 0, 0, 0); \
  } \
  __builtin_amdgcn_s_setprio(0)
#define BAR() \
  __builtin_amdgcn_sched_barrier(0); \
  __builtin_amdgcn_s_barrier(); \
  asm volatile("" ::: "memory"); \
  __builtin_amdgcn_sched_barrier(0)
#define VM3() \
  __builtin_amdgcn_sched_barrier(0); \
  asm volatile("s_waitcnt vmcnt(3)" ::: "memory"); \
  __builtin_amdgcn_sched_barrier(0)
#define VM0() \
  __builtin_amdgcn_sched_barrier(0); \
  asm volatile("s_waitcnt vmcnt(0)" ::: "memory"); \
  __builtin_amdgcn_sched_barrier(0)

  floatx4 acc[4][4];
#pragma unroll
  for (int m = 0; m < 4; ++m)
#pragma unroll
    for (int n = 0; n < 4; ++n) acc[m][n] = (floatx4){0.f, 0.f, 0.f, 0.f};
  shortx8 af[4], bf0, bf1;

  // prologue: kt0 all 4 units (6 loads) + kt1 {Akk0, Bnh0} (3 loads);
  // VM3 drains kt0, leaves kt1's 3 in flight.
  SA(0, 0, 0);
  SB(0, 0, 0);
  SA(0, 1, 0);
  SB(0, 1, 0);
  SA(1, 0, 64);
  SB(1, 0, 64);
  VM3();
  BAR();

#pragma unroll 1
  for (int i = 0; i < 3; ++i) {
    const unsigned k1 = (unsigned)(2 * i + 1) * 64u;
    const unsigned k2 = k1 + 64u, k3 = k1 + 128u;
    // P1
    SA(1, 1, k1);
    LOAD_AF(0, 0); LOAD_BF(0, 0, 0); MFMA8(0);
    BAR();
    // P2
    SB(1, 1, k1);
    LOAD_BF(0, 1, 0); MFMA8(1);
    BAR();
    // P3
    SA(0, 0, k2);
    LOAD_AF(1, 0); LOAD_BF(1, 0, 0); MFMA8(0);
    BAR();
    // P4
    SB(0, 0, k2);
    LOAD_BF(1, 1, 0); MFMA8(1);
    VM3();
    BAR();
    // P5
    SA(0, 1, k2);
    LOAD_AF(0, 1); LOAD_BF(0, 0, 1); MFMA8(0);
    BAR();
    // P6
    SB(0, 1, k2);
    LOAD_BF(0, 1, 1); MFMA8(1);
    BAR();
    // P7
    SA(1, 0, k3);
    LOAD_AF(1, 1); LOAD_BF(1, 0, 1); MFMA8(0);
    BAR();
    // P8
    SB(1, 0, k3);
    LOAD_BF(1, 1, 1); MFMA8(1);
    VM3();
    BAR();
  }
  // tail iter (i=3): kt6 in d0, kt7 in d1; only P1/P2 stage (kt7 tail units)
  {
    SA(1, 1, 448);                                 // Akk1(kt7)
    LOAD_AF(0, 0); LOAD_BF(0, 0, 0); MFMA8(0);
    BAR();
    SB(1, 1, 448);                                 // Bnh1(kt7)
    LOAD_BF(0, 1, 0); MFMA8(1);
    BAR();
    LOAD_AF(1, 0); LOAD_BF(1, 0, 0); MFMA8(0);
    BAR();
    LOAD_BF(1, 1, 0); MFMA8(1);
    VM0();                                         // kt7 complete
    BAR();
    LOAD_AF(0, 1); LOAD_BF(0, 0, 1); MFMA8(0);
    BAR();
    LOAD_BF(0, 1, 1); MFMA8(1);
    BAR();
    LOAD_AF(1, 1); LOAD_BF(1, 0, 1); MFMA8(0);
    BAR();
    LOAD_BF(1, 1, 1); MFMA8(1);
  }

  // epilogue: register-only -> no barrier needed
  const int er0 = m0 + (wv >> 2) * 64 + (lane >> 4) * 4;
  const int ec0 = n0 + (wv & 3) * 64 + lr;
#pragma unroll
  for (int m = 0; m < 4; ++m)
#pragma unroll
    for (int n = 0; n < 4; ++n)
#pragma unroll
      for (int r = 0; r < 4; ++r) {
        float vv = acc[m][n][r];
        if (isq) vv = fmaxf(vv, 0.f);
        C[(u64)(er0 + m * 16 + r) * 1024 + (u64)(ec0 + n * 16)] = f2bf(vv);
      }
#undef SA
#undef SB
#undef LOAD_AF
#undef LOAD_BF
#undef MFMA8
#undef BAR
#undef VM3
#undef VM0
}

// fused logits for both scales: grid (64, 3).
__global__ __launch_bounds__(256, 2) void k_logits(
    const u16* __restrict__ rq, const u16* __restrict__ w20,
    const u16* __restrict__ w21, float* __restrict__ lg) {
  __shared__ __align__(16) u16 lA[128 * 32];
  __shared__ __align__(16) u16 lB[128 * 32];
  const int am = blockIdx.x * 128;
  const int y = blockIdx.y;
  const u16* A = rq + (u64)am * 1024 + (y == 0 ? 0 : 512);
  const u16* W = (y == 0) ? w20 : (w21 + (u64)(y - 1) * 128 * 512);
  float* Cf = lg + (u64)am * 384 + y * 128;
  gemm_core<0>(A, 1024, W, 512, Cf, nullptr, 384, 0, lA, lB);
}

// final projection: grid (64, 4), fp32 out.
__global__ __launch_bounds__(256, 2) void k_final(
    const u16* __restrict__ xb, const u16* __restrict__ wo,
    float* __restrict__ out) {
  __shared__ __align__(16) u16 lA[128 * 32];
  __shared__ __align__(16) u16 lB[128 * 32];
  const int am = blockIdx.x * 128, bn = blockIdx.y * 128;
  gemm_core<0>(xb + (u64)am * 512, 512, wo + (u64)bn * 512, 512,
               out + (u64)am * 512 + bn, nullptr, 512, 0, lA, lB);
}

// ---------------------------------------------------------------------------
// MFMA attention (verbatim, round-9 d-SPLIT version)
// ---------------------------------------------------------------------------
#define VLDT 136
#define ESL 152

template <int CS, int CHUNK>
__device__ __forceinline__ void attn_mfma_pass(
    const float* __restrict__ lg,   // pre-offset to scale+head col base, row stride 384
    const u16* __restrict__ vbh,    // vcat + scale*512 + h*128 + dh*64, row stride 1024
    int bb, int t0, float swv,
    u16* vT, u16* es16, float* invsum, floatx4 (&o)[4]) {
  constexpr int HALF = (CS - 1) / 2;
  constexpr int NW = 64 + CS - 1;  // valid window rows (94 / 124)
  const int tid = threadIdx.x;
  const int wave = tid >> 6, lane = tid & 63;
  const int lr = lane & 15, kq = (lane >> 4) * 8;

  __syncthreads();  // prior consumers done with vT/es16/invsum

  // stage V-window (64 d-cols) transposed+swizzled; coalesced 128B segments.
#pragma unroll
  for (int it = 0; it < 4; ++it) {
    int idx = it * 256 + tid;
    int r = idx >> 3;              // 0..127
    int dl8 = (idx & 7) * 8;       // 0..56 (local d chunk)
    int t = t0 + r - HALF;
    uint4 u = make_uint4(0u, 0u, 0u, 0u);
    if (r < NW && t >= 0 && t < 2048)
      u = *(const uint4*)&vbh[(u64)(bb + t) * 1024 + dl8];
    int sb = (((r >> 3) ^ ((dl8 >> 3) & 7)) << 3) + (r & 7);
    u16* wp = &vT[dl8 * VLDT + sb];
    const u16* us = (const u16*)&u;
#pragma unroll
    for (int j = 0; j < 8; ++j) wp[j * VLDT] = us[j];
  }

  // exp (chunked global reads) + complement zeros + quad row-sum via shfl
  {
    int tt = tid >> 2, qq = tid & 3;
    u16* row = es16 + tt * ESL;
    const int lo = tt, hi = tt + CS;
#pragma unroll
    for (int j = 0; j < 32; ++j) {
      int x = qq * 32 + j;
      if (x < lo || x >= hi) row[x] = 0;
    }
    const float* lrow = lg + (u64)(bb + t0 + tt) * 384 + qq * CHUNK;
    float ps = 0.f;
#pragma unroll
    for (int j = 0; j < CHUNK; ++j) {
      int c = qq * CHUNK + j;
      if (c < CS) {
        float ev = __expf(lrow[j]);
        row[lo + c] = f2bf(ev);
        ps += ev;
      }
    }
    ps += __shfl_xor(ps, 1, 64);
    ps += __shfl_xor(ps, 2, 64);
    if (qq == 0) invsum[tt] = swv / ps;
  }
  __syncthreads();

  // MFMA: wave w owns output rows w*16..w*16+15; band limits k-blocks.
  const int kb_lo = (wave * 16) >> 5;
  const int kb_hi = (wave * 16 + 15 + CS - 1) >> 5;
  floatx4 acc[4];
#pragma unroll
  for (int nt = 0; nt < 4; ++nt) acc[nt] = (floatx4){0.f, 0.f, 0.f, 0.f};
  for (int kb = kb_lo; kb <= kb_hi; ++kb) {
    shortx8 af = *(const shortx8*)&es16[(wave * 16 + lr) * ESL + kb * 32 + kq];
    int rb8 = kb * 4 + (lane >> 4);
#pragma unroll
    for (int nt = 0; nt < 4; ++nt) {
      int d_row = nt * 16 + lr;   // 0..63 local d
      int blk = (rb8 ^ ((d_row >> 3) & 7)) << 3;
      shortx8 bf8 = *(const shortx8*)&vT[d_row * VLDT + blk];
      acc[nt] = __builtin_amdgcn_mfma_f32_16x16x32_bf16(af, bf8, acc[nt], 0, 0, 0);
    }
  }
  // fold swv/rowsum, accumulate into persistent o (C-layout rows)
  float invs[4];
#pragma unroll
  for (int rr = 0; rr < 4; ++rr)
    invs[rr] = invsum[wave * 16 + (lane >> 4) * 4 + rr];
#pragma unroll
  for (int nt = 0; nt < 4; ++nt)
#pragma unroll
    for (int rr = 0; rr < 4; ++rr) o[nt][rr] += acc[nt][rr] * invs[rr];
}

__global__ __launch_bounds__(256, 2) void k_attn4(
    const float* __restrict__ lg, const u16* __restrict__ vcat,
    const float* __restrict__ swp, u16* __restrict__ xbw) {
  __shared__ __align__(16) u16 vT[64 * VLDT];
  __shared__ __align__(16) u16 es16[64 * ESL];
  __shared__ float invsum[64];
  const int tid = threadIdx.x;
  const int wave = tid >> 6, lane = tid & 63;
  const int lr = lane & 15;
  const int t0 = blockIdx.x * 64;
  const int h = blockIdx.y >> 1, dh = blockIdx.y & 1;
  const int b = blockIdx.z;
  const int bb = b * 2048;
  const int m0 = bb + t0;

  float a0 = swp[0], a1 = swp[1];
  float mx = fmaxf(a0, a1);
  float e0 = __expf(a0 - mx), e1 = __expf(a1 - mx);
  float inv = 1.f / (e0 + e1);

  floatx4 o[4];
#pragma unroll
  for (int nt = 0; nt < 4; ++nt) o[nt] = (floatx4){0.f, 0.f, 0.f, 0.f};

  attn_mfma_pass<31, 8>(lg + h * 31, vcat + h * 128 + dh * 64,
                        bb, t0, e0 * inv, vT, es16, invsum, o);
  attn_mfma_pass<61, 16>(lg + 128 + h * 61, vcat + 512 + h * 128 + dh * 64,
                         bb, t0, e1 * inv, vT, es16, invsum, o);

  // epilogue: stage bf16 output half-tile in es16 (reuse), coalesced stores
  __syncthreads();
#pragma unroll
  for (int nt = 0; nt < 4; ++nt)
#pragma unroll
    for (int rr = 0; rr < 4; ++rr) {
      int trow = wave * 16 + (lane >> 4) * 4 + rr;
      es16[trow * ESL + nt * 16 + lr] = f2bf(o[nt][rr]);
    }
  __syncthreads();
#pragma unroll
  for (int rep = 0; rep < 2; ++rep) {
    int idx = rep * 256 + tid;
    int trow = idx >> 3;            // 0..63
    int col8 = (idx & 7) * 8;       // 0..56
    uint4 u = *(const uint4*)&es16[trow * ESL + col8];
    *(uint4*)&xbw[(u64)(m0 + trow) * 512 + h * 128 + dh * 64 + col8] = u;
  }
}

// ---------------------------------------------------------------------------
extern "C" void kernel_launch(void* const* d_in, const int* in_sizes, int n_in,
                              void* d_out, int out_size, void* d_ws, size_t ws_size,
                              hipStream_t stream) {
  const float* q   = (const float*)d_in[0];
  const float* v   = (const float*)d_in[2];
  const float* w10 = (const float*)d_in[3];
  const float* w11 = (const float*)d_in[4];
  const float* w20 = (const float*)d_in[5];
  const float* w21 = (const float*)d_in[6];
  const float* w30 = (const float*)d_in[7];
  const float* w31 = (const float*)d_in[8];
  const float* sw  = (const float*)d_in[9];
  const float* wo  = (const float*)d_in[10];
  float* out = (float*)d_out;

  u16* base  = (u16*)d_ws;
  u16* qb    = base;
  u16* vb    = base + 4194304;
  u16* w1cat = base + 8388608;
  u16* w3cat = base + 8912896;
  u16* wob   = base + 9437184;
  u16* w2b0  = base + 9699328;
  u16* w2b1  = base + 9764864;
  char* fb = (char*)d_ws + 19791872;
  float* logitsC = (float*)fb;            // [8192][384]
  u16* rqcat = (u16*)(logitsC + 3145728); // [8192][1024]
  u16* vcat  = rqcat + 8388608;           // [8192][1024]
  u16* xb    = vcat + 8388608;            // [8192][512]
  // total ws use: 74,317,824 bytes

  convert_all<<<dim3(9664), dim3(256), 0, stream>>>(q, v, w10, w11, w30, w31, wo, w20, w21, base);

  dim3 blk(256);
  k_qv10<<<dim3(512), dim3(512), 0, stream>>>(qb, vb, w1cat, w3cat, rqcat, vcat);
  k_logits<<<dim3(64, 3), blk, 0, stream>>>(rqcat, w2b0, w2b1, logitsC);
  k_attn4<<<dim3(32, 8, 4), blk, 0, stream>>>(logitsC, vcat, sw, xb);
  k_final<<<dim3(64, 4), blk, 0, stream>>>(xb, wob, out);
}

// Round 10
// 167.425 us; speedup vs baseline: 1.0359x; 1.0328x over previous
//
#include <hip/hip_runtime.h>

typedef unsigned short u16;
typedef unsigned long long u64;
typedef float floatx4 __attribute__((ext_vector_type(4)));
typedef short shortx8 __attribute__((ext_vector_type(8)));

__device__ inline u16 f2bf(float f) {
  unsigned u = __float_as_uint(f);
  u += 0x7fffu + ((u >> 16) & 1u);
  return (u16)(u >> 16);
}

// async global->LDS, 16B per lane (wave-uniform LDS base + lane*16).
__device__ __forceinline__ void gl16(const u16* g, const u16* l) {
  __builtin_amdgcn_global_load_lds(
      (const __attribute__((address_space(1))) unsigned int*)(u64)(const void*)g,
      (__attribute__((address_space(3))) unsigned int*)(unsigned)(u64)(const void*)l,
      16, 0, 0);
}

// ---------------------------------------------------------------------------
// fp32 -> bf16 conversion (full: q/v + weights)
// ushort offsets: qb 0 | vb 4194304 | w1cat 8388608 | w3cat 8912896 |
// wob 9437184 | w2b0p 9699328 (128x512) | w2b1p 9764864 (256x512) | end 9895936
// ---------------------------------------------------------------------------
__global__ __launch_bounds__(256) void convert_all(
    const float* __restrict__ q, const float* __restrict__ v,
    const float* __restrict__ w10, const float* __restrict__ w11,
    const float* __restrict__ w30, const float* __restrict__ w31,
    const float* __restrict__ wo, const float* __restrict__ w20,
    const float* __restrict__ w21, u16* __restrict__ base) {
  size_t e = ((size_t)blockIdx.x * 256 + threadIdx.x) * 4;
  const float* src;
  u16* dst;
  size_t le;
  unsigned prows;
  if (e < 4194304ull)      { src = q;   dst = base;            le = e;            prows = 0x7fffffffu; }
  else if (e < 8388608ull) { src = v;   dst = base + 4194304;  le = e - 4194304;  prows = 0x7fffffffu; }
  else if (e < 8650752ull) { src = w10; dst = base + 8388608;  le = e - 8388608;  prows = 0x7fffffffu; }
  else if (e < 8912896ull) { src = w11; dst = base + 8650752;  le = e - 8650752;  prows = 0x7fffffffu; }
  else if (e < 9175040ull) { src = w30; dst = base + 8912896;  le = e - 8912896;  prows = 0x7fffffffu; }
  else if (e < 9437184ull) { src = w31; dst = base + 9175040;  le = e - 9175040;  prows = 0x7fffffffu; }
  else if (e < 9699328ull) { src = wo;  dst = base + 9437184;  le = e - 9437184;  prows = 0x7fffffffu; }
  else if (e < 9764864ull) { src = w20; dst = base + 9699328;  le = e - 9699328;  prows = 124; }
  else                     { src = w21; dst = base + 9764864;  le = e - 9764864;  prows = 244; }
  float4 val = make_float4(0.f, 0.f, 0.f, 0.f);
  if ((unsigned)(le >> 9) < prows) val = *(const float4*)(src + le);
  unsigned p0 = (unsigned)f2bf(val.x) | ((unsigned)f2bf(val.y) << 16);
  unsigned p1 = (unsigned)f2bf(val.z) | ((unsigned)f2bf(val.w) << 16);
  *(uint2*)(dst + le) = make_uint2(p0, p1);
}

// ---------------------------------------------------------------------------
// m97-structure GEMM core (kept for k_logits / k_final)
// ---------------------------------------------------------------------------
template <int OUTBF>
__device__ __forceinline__ void gemm_core(
    const u16* __restrict__ A, int lda, const u16* __restrict__ W, int ldw,
    float* __restrict__ Cf, u16* __restrict__ Cb, int ldc, int relu,
    u16* lA, u16* lB) {
  const int tid = threadIdx.x;
  const int wave = tid >> 6, lane = tid & 63;
  const int wm = (wave >> 1) * 64, wn = (wave & 1) * 64;
  const int lr = lane & 15, kq = (lane >> 4) * 8;
  const int sr = lane >> 2, sc = (lane & 3) * 8;

  floatx4 acc[4][4];
#pragma unroll
  for (int i = 0; i < 4; ++i)
#pragma unroll
    for (int j = 0; j < 4; ++j) acc[i][j] = (floatx4){0.f, 0.f, 0.f, 0.f};

  const u16* ga0 = A + (u64)(wave * 32 + sr) * lda + sc;
  const u16* ga1 = A + (u64)(wave * 32 + 16 + sr) * lda + sc;
  const u16* gb0 = W + (u64)(wave * 32 + sr) * ldw + sc;
  const u16* gb1 = W + (u64)(wave * 32 + 16 + sr) * ldw + sc;
  u16* la0 = lA + (wave * 32) * 32;
  u16* la1 = lA + (wave * 32 + 16) * 32;
  u16* lb0 = lB + (wave * 32) * 32;
  u16* lb1 = lB + (wave * 32 + 16) * 32;

  for (int k0 = 0; k0 < 512; k0 += 32) {
    __syncthreads();
    gl16(ga0 + k0, la0);
    gl16(ga1 + k0, la1);
    gl16(gb0 + k0, lb0);
    gl16(gb1 + k0, lb1);
    __syncthreads();
    shortx8 af[4], bf8[4];
#pragma unroll
    for (int i = 0; i < 4; ++i) {
      af[i] = *(const shortx8*)&lA[(wm + i * 16 + lr) * 32 + kq];
      bf8[i] = *(const shortx8*)&lB[(wn + i * 16 + lr) * 32 + kq];
    }
#pragma unroll
    for (int mi = 0; mi < 4; ++mi)
#pragma unroll
      for (int ni = 0; ni < 4; ++ni)
        acc[mi][ni] = __builtin_amdgcn_mfma_f32_16x16x32_bf16(af[mi], bf8[ni], acc[mi][ni], 0, 0, 0);
  }
  const int er = wm + (lane >> 4) * 4;
  const int ec = wn + lr;
#pragma unroll
  for (int mi = 0; mi < 4; ++mi)
#pragma unroll
    for (int ni = 0; ni < 4; ++ni)
#pragma unroll
      for (int r = 0; r < 4; ++r) {
        float vv = acc[mi][ni][r];
        if (relu) vv = fmaxf(vv, 0.f);
        u64 off = (u64)(er + mi * 16 + r) * (u64)ldc + (u64)(ec + ni * 16);
        if (OUTBF) Cb[off] = f2bf(vv);
        else Cf[off] = vv;
      }
}

// ---------------------------------------------------------------------------
// k_qv8 — round-6 best-measured variant (total 169.80 us): 256x256/BK=64/
// 8-wave/8-phase ring, gl16 A+B from preconverted bf16, static 128 KB LDS.
// ---------------------------------------------------------------------------
__global__ __launch_bounds__(512, 2) void k_qv8(
    const u16* __restrict__ qb, const u16* __restrict__ vb,
    const u16* __restrict__ w1, const u16* __restrict__ w3,
    u16* __restrict__ rq, u16* __restrict__ vc) {
  __shared__ __align__(16) u16 lds[65536];  // 128 KB static
  const int bid = blockIdx.x;
  const int bx = (bid & 7) * 32 + (bid >> 3);  // XCD swizzle, 256%8==0 bijective
  const bool isq = bx < 128;
  const int lb = isq ? bx : bx - 128;
  const int m0 = (lb >> 2) * 256;
  const int n0 = (lb & 3) * 256;
  const u16* __restrict__ A = isq ? qb : vb;   // [8192][512]
  const u16* __restrict__ W = isq ? w1 : w3;   // [1024][512]
  u16* __restrict__ C = isq ? rq : vc;         // [8192][1024]

  const int tid = threadIdx.x;
  const int wv = tid >> 6, lane = tid & 63;
  const int wr = wv >> 2, wc = wv & 3;
  const int lr = lane & 15, kq = lane >> 4;

  const unsigned Ca = ((unsigned)((lr >> 1) & 7)) << 3;
  const unsigned afb = ((unsigned)((wr * 128 + lr) * 32 + kq * 8)) ^ Ca;
  const unsigned bfb = ((unsigned)((wc * 32 + lr) * 32 + kq * 8)) ^ Ca;

  const unsigned u0 = (unsigned)(wv * 1024 + lane * 8);
  const unsigned u1 = u0 + 512;
  const unsigned g0 = u0 ^ (((u0 >> 6) & 7) << 3);
  const unsigned g1 = u1 ^ (((u1 >> 6) & 7) << 3);
  const unsigned gA0 = (unsigned)(m0 + (int)(g0 >> 5)) * 512u + (g0 & 31);
  const unsigned gA1 = (unsigned)(m0 + (int)(g1 >> 5)) * 512u + (g1 & 31);
  const unsigned rp0 = (g0 >> 5) & 127, rp1 = (g1 >> 5) & 127;
  const unsigned gB0n0 = (unsigned)(n0 + (int)((rp0 >> 5) * 64 + (rp0 & 31))) * 512u
                         + (g0 >> 12) * 32 + (g0 & 31);
  const unsigned gB1n0 = (unsigned)(n0 + (int)((rp1 >> 5) * 64 + (rp1 & 31))) * 512u
                         + (g1 >> 12) * 32 + (g1 & 31);
  const unsigned gB0n1 = gB0n0 + 32u * 512u;
  const unsigned gB1n1 = gB1n0 + 32u * 512u;
  const unsigned wvo = (unsigned)wv * 1024u;

#define SA(d, kk, ga, gb, ko) \
  gl16(A + (ga) + (ko), lds + (d)*16384 + (kk)*8192 + wvo); \
  gl16(A + (gb) + (ko), lds + (d)*16384 + (kk)*8192 + wvo + 512)
#define SB(d, nh, ga, gb, ko) \
  gl16(W + (ga) + (ko), lds + 32768 + (d)*16384 + (nh)*8192 + wvo); \
  gl16(W + (gb) + (ko), lds + 32768 + (d)*16384 + (nh)*8192 + wvo + 512)
#define LOAD_AF(kk, d) \
  _Pragma("unroll") \
  for (int m = 0; m < 8; ++m) \
    af[m] = *(const shortx8*)&lds[(d)*16384 + (kk)*8192 + afb + (unsigned)m * 512]
#define LOAD_BF(kk, nh, d) \
  bf0 = *(const shortx8*)&lds[32768 + (d)*16384 + (nh)*8192 + (kk)*4096 + bfb]; \
  bf1 = *(const shortx8*)&lds[32768 + (d)*16384 + (nh)*8192 + (kk)*4096 + bfb + 512]
#define MFMA16(nh) \
  __builtin_amdgcn_s_setprio(1); \
  _Pragma("unroll") \
  for (int m = 0; m < 8; ++m) { \
    acc[m][(nh)*2]   = __builtin_amdgcn_mfma_f32_16x16x32_bf16(af[m], bf0, acc[m][(nh)*2], 0, 0, 0); \
    acc[m][(nh)*2+1] = __builtin_amdgcn_mfma_f32_16x16x32_bf16(af[m], bf1, acc[m][(nh)*2+1], 0, 0, 0); \
  } \
  __builtin_amdgcn_s_setprio(0)
#define BAR() \
  __builtin_amdgcn_sched_barrier(0); \
  __builtin_amdgcn_s_barrier(); \
  asm volatile("" ::: "memory"); \
  __builtin_amdgcn_sched_barrier(0)
#define WAITVM4() \
  __builtin_amdgcn_sched_barrier(0); \
  asm volatile("s_waitcnt vmcnt(4)" ::: "memory"); \
  __builtin_amdgcn_sched_barrier(0)
#define WAITVM0() \
  __builtin_amdgcn_sched_barrier(0); \
  asm volatile("s_waitcnt vmcnt(0)" ::: "memory"); \
  __builtin_amdgcn_sched_barrier(0)

  floatx4 acc[8][4];
#pragma unroll
  for (int m = 0; m < 8; ++m)
#pragma unroll
    for (int n = 0; n < 4; ++n) acc[m][n] = (floatx4){0.f, 0.f, 0.f, 0.f};
  shortx8 af[8], bf0, bf1;

  SA(0, 0, gA0, gA1, 0);
  SB(0, 0, gB0n0, gB1n0, 0);
  SA(0, 1, gA0 + 32, gA1 + 32, 0);
  SB(0, 1, gB0n1, gB1n1, 0);
  SA(1, 0, gA0, gA1, 64);
  SB(1, 0, gB0n0, gB1n0, 64);
  WAITVM4();
  BAR();

#pragma unroll 1
  for (int i = 0; i < 3; ++i) {
    const unsigned k1 = (unsigned)(2 * i + 1) * 64u;
    const unsigned k2 = k1 + 64u, k3 = k1 + 128u;
    SA(1, 1, gA0 + 32, gA1 + 32, k1);
    LOAD_AF(0, 0); LOAD_BF(0, 0, 0); MFMA16(0);
    BAR();
    SB(1, 1, gB0n1, gB1n1, k1);
    LOAD_BF(0, 1, 0); MFMA16(1);
    BAR();
    SA(0, 0, gA0, gA1, k2);
    LOAD_AF(1, 0); LOAD_BF(1, 0, 0); MFMA16(0);
    BAR();
    SB(0, 0, gB0n0, gB1n0, k2);
    LOAD_BF(1, 1, 0); MFMA16(1);
    WAITVM4();
    BAR();
    SA(0, 1, gA0 + 32, gA1 + 32, k2);
    LOAD_AF(0, 1); LOAD_BF(0, 0, 1); MFMA16(0);
    BAR();
    SB(0, 1, gB0n1, gB1n1, k2);
    LOAD_BF(0, 1, 1); MFMA16(1);
    BAR();
    SA(1, 0, gA0, gA1, k3);
    LOAD_AF(1, 1); LOAD_BF(1, 0, 1); MFMA16(0);
    BAR();
    SB(1, 0, gB0n0, gB1n0, k3);
    LOAD_BF(1, 1, 1); MFMA16(1);
    WAITVM4();
    BAR();
  }
  {
    const unsigned k1 = 448u;
    SA(1, 1, gA0 + 32, gA1 + 32, k1);              // Akk1(7)
    LOAD_AF(0, 0); LOAD_BF(0, 0, 0); MFMA16(0);
    BAR();
    SB(1, 1, gB0n1, gB1n1, k1);                    // Bnh1(7)
    LOAD_BF(0, 1, 0); MFMA16(1);
    BAR();
    LOAD_AF(1, 0); LOAD_BF(1, 0, 0); MFMA16(0);
    BAR();
    LOAD_BF(1, 1, 0); MFMA16(1);
    WAITVM0();
    BAR();
    LOAD_AF(0, 1); LOAD_BF(0, 0, 1); MFMA16(0);
    BAR();
    LOAD_BF(0, 1, 1); MFMA16(1);
    BAR();
    LOAD_AF(1, 1); LOAD_BF(1, 0, 1); MFMA16(0);
    BAR();
    LOAD_BF(1, 1, 1); MFMA16(1);
  }

  const int er0 = m0 + wr * 128 + (lane >> 4) * 4;
  const int ec0 = n0 + wc * 64 + lr;
#pragma unroll
  for (int m = 0; m < 8; ++m)
#pragma unroll
    for (int n = 0; n < 4; ++n)
#pragma unroll
      for (int r = 0; r < 4; ++r) {
        float vv = acc[m][n][r];
        if (isq) vv = fmaxf(vv, 0.f);
        C[(u64)(er0 + m * 16 + r) * 1024 + (u64)(ec0 + n * 16)] = f2bf(vv);
      }
#undef SA
#undef SB
#undef LOAD_AF
#undef LOAD_BF
#undef MFMA16
#undef BAR
#undef WAITVM4
#undef WAITVM0
}

// fused logits for both scales: grid (64, 3).
__global__ __launch_bounds__(256, 2) void k_logits(
    const u16* __restrict__ rq, const u16* __restrict__ w20,
    const u16* __restrict__ w21, float* __restrict__ lg) {
  __shared__ __align__(16) u16 lA[128 * 32];
  __shared__ __align__(16) u16 lB[128 * 32];
  const int am = blockIdx.x * 128;
  const int y = blockIdx.y;
  const u16* A = rq + (u64)am * 1024 + (y == 0 ? 0 : 512);
  const u16* W = (y == 0) ? w20 : (w21 + (u64)(y - 1) * 128 * 512);
  float* Cf = lg + (u64)am * 384 + y * 128;
  gemm_core<0>(A, 1024, W, 512, Cf, nullptr, 384, 0, lA, lB);
}

// final projection: grid (64, 4), fp32 out.
__global__ __launch_bounds__(256, 2) void k_final(
    const u16* __restrict__ xb, const u16* __restrict__ wo,
    float* __restrict__ out) {
  __shared__ __align__(16) u16 lA[128 * 32];
  __shared__ __align__(16) u16 lB[128 * 32];
  const int am = blockIdx.x * 128, bn = blockIdx.y * 128;
  gemm_core<0>(xb + (u64)am * 512, 512, wo + (u64)bn * 512, 512,
               out + (u64)am * 512 + bn, nullptr, 512, 0, lA, lB);
}

// ---------------------------------------------------------------------------
// MFMA attention, dh-MERGE (round-9 fixed): one 512-thread block per
// (t-tile, head, batch) — grid (32, 4, 4); h = blockIdx.y in 0..3 (4 heads
// per scale, head_dim 128). R9's failure was grid y=8: blocks h=4..7 read
// out-of-range logits/V and wrote past the 512-wide xbw rows. Kernel body
// unchanged from R9 (audited clean). exp+lg-read+rowsum runs once per
// (h,t0,b) on tid<256 verbatim -> bit-identical numerics to the d-SPLIT.
// LDS 54.5 KB -> 2 blocks/CU, 16 waves/CU.
// ---------------------------------------------------------------------------
#define VLDT 136
#define ESL 152

template <int CS, int CHUNK>
__device__ __forceinline__ void attn_pass512(
    const float* __restrict__ lg,   // pre-offset to scale+head col base, row stride 384
    const u16* __restrict__ vbh,    // vcat + scale*512 + h*128, row stride 1024
    int bb, int t0, float swv,
    u16* vT, u16* es16, float* invsum, floatx4 (&o)[4]) {
  constexpr int HALF = (CS - 1) / 2;
  constexpr int NW = 64 + CS - 1;  // valid window rows (94 / 124)
  const int tid = threadIdx.x;
  const int wave = tid >> 6, lane = tid & 63;
  const int lr = lane & 15, kq = (lane >> 4) * 8;
  const int wrow = wave & 3;       // output row-group
  const int dhw = wave >> 2;       // d-half (0: d 0..63, 1: d 64..127)

  __syncthreads();  // prior consumers done with vT/es16/invsum

  // stage V-window, FULL 128 d-cols, transposed+swizzled. 4 iters x 512 thr:
  // idx -> r = idx>>4 (0..127), dl8 = (idx&15)*8 (0..120).
#pragma unroll
  for (int it = 0; it < 4; ++it) {
    int idx = it * 512 + tid;
    int r = idx >> 4;
    int dl8 = (idx & 15) * 8;
    int t = t0 + r - HALF;
    uint4 u = make_uint4(0u, 0u, 0u, 0u);
    if (r < NW && t >= 0 && t < 2048)
      u = *(const uint4*)&vbh[(u64)(bb + t) * 1024 + dl8];
    int sb = (((r >> 3) ^ ((dl8 >> 3) & 7)) << 3) + (r & 7);
    u16* wp = &vT[dl8 * VLDT + sb];
    const u16* us = (const u16*)&u;
#pragma unroll
    for (int j = 0; j < 8; ++j) wp[j * VLDT] = us[j];
  }

  // exp + complement zeros + quad row-sum: tid<256 only, VERBATIM round-8
  // lane decomposition (tt = tid>>2, qq = tid&3) -> bit-identical numerics.
  if (tid < 256) {
    int tt = tid >> 2, qq = tid & 3;
    u16* row = es16 + tt * ESL;
    const int lo = tt, hi = tt + CS;
#pragma unroll
    for (int j = 0; j < 32; ++j) {
      int x = qq * 32 + j;
      if (x < lo || x >= hi) row[x] = 0;
    }
    const float* lrow = lg + (u64)(bb + t0 + tt) * 384 + qq * CHUNK;
    float ps = 0.f;
#pragma unroll
    for (int j = 0; j < CHUNK; ++j) {
      int c = qq * CHUNK + j;
      if (c < CS) {
        float ev = __expf(lrow[j]);
        row[lo + c] = f2bf(ev);
        ps += ev;
      }
    }
    ps += __shfl_xor(ps, 1, 64);
    ps += __shfl_xor(ps, 2, 64);
    if (qq == 0) invsum[tt] = swv / ps;
  }
  __syncthreads();

  // MFMA: wave (wrow,dhw) owns output rows wrow*16..+15, d-cols dhw*64+nt*16.
  const int kb_lo = (wrow * 16) >> 5;
  const int kb_hi = (wrow * 16 + 15 + CS - 1) >> 5;
  floatx4 acc[4];
#pragma unroll
  for (int nt = 0; nt < 4; ++nt) acc[nt] = (floatx4){0.f, 0.f, 0.f, 0.f};
  for (int kb = kb_lo; kb <= kb_hi; ++kb) {
    shortx8 af = *(const shortx8*)&es16[(wrow * 16 + lr) * ESL + kb * 32 + kq];
    int rb8 = kb * 4 + (lane >> 4);
#pragma unroll
    for (int nt = 0; nt < 4; ++nt) {
      int d_row = dhw * 64 + nt * 16 + lr;   // 0..127
      int blk = (rb8 ^ ((d_row >> 3) & 7)) << 3;
      shortx8 bf8 = *(const shortx8*)&vT[d_row * VLDT + blk];
      acc[nt] = __builtin_amdgcn_mfma_f32_16x16x32_bf16(af, bf8, acc[nt], 0, 0, 0);
    }
  }
  float invs[4];
#pragma unroll
  for (int rr = 0; rr < 4; ++rr)
    invs[rr] = invsum[wrow * 16 + (lane >> 4) * 4 + rr];
#pragma unroll
  for (int nt = 0; nt < 4; ++nt)
#pragma unroll
    for (int rr = 0; rr < 4; ++rr) o[nt][rr] += acc[nt][rr] * invs[rr];
}

__global__ __launch_bounds__(512, 2) void k_attn4(
    const float* __restrict__ lg, const u16* __restrict__ vcat,
    const float* __restrict__ swp, u16* __restrict__ xbw) {
  __shared__ __align__(16) u16 vT[128 * VLDT];
  __shared__ __align__(16) u16 es16[64 * ESL];
  __shared__ float invsum[64];
  const int tid = threadIdx.x;
  const int wave = tid >> 6, lane = tid & 63;
  const int lr = lane & 15;
  const int wrow = wave & 3, dhw = wave >> 2;
  const int t0 = blockIdx.x * 64;
  const int h = blockIdx.y;            // 0..3 — 4 heads per scale, d=128 each
  const int b = blockIdx.z;
  const int bb = b * 2048;
  const int m0 = bb + t0;

  float a0 = swp[0], a1 = swp[1];
  float mx = fmaxf(a0, a1);
  float e0 = __expf(a0 - mx), e1 = __expf(a1 - mx);
  float inv = 1.f / (e0 + e1);

  floatx4 o[4];
#pragma unroll
  for (int nt = 0; nt < 4; ++nt) o[nt] = (floatx4){0.f, 0.f, 0.f, 0.f};

  attn_pass512<31, 8>(lg + h * 31, vcat + h * 128,
                      bb, t0, e0 * inv, vT, es16, invsum, o);
  attn_pass512<61, 16>(lg + 128 + h * 61, vcat + 512 + h * 128,
                       bb, t0, e1 * inv, vT, es16, invsum, o);

  // epilogue: stage bf16 output 64x128 tile in es16 (ESL=152 >= 128 cols)
  __syncthreads();
#pragma unroll
  for (int nt = 0; nt < 4; ++nt)
#pragma unroll
    for (int rr = 0; rr < 4; ++rr) {
      int trow = wrow * 16 + (lane >> 4) * 4 + rr;
      es16[trow * ESL + dhw * 64 + nt * 16 + lr] = f2bf(o[nt][rr]);
    }
  __syncthreads();
#pragma unroll
  for (int rep = 0; rep < 2; ++rep) {
    int idx = rep * 512 + tid;
    int trow = idx >> 4;            // 0..63
    int col8 = (idx & 15) * 8;      // 0..120
    uint4 u = *(const uint4*)&es16[trow * ESL + col8];
    *(uint4*)&xbw[(u64)(m0 + trow) * 512 + h * 128 + col8] = u;
  }
}

// ---------------------------------------------------------------------------
extern "C" void kernel_launch(void* const* d_in, const int* in_sizes, int n_in,
                              void* d_out, int out_size, void* d_ws, size_t ws_size,
                              hipStream_t stream) {
  const float* q   = (const float*)d_in[0];
  const float* v   = (const float*)d_in[2];
  const float* w10 = (const float*)d_in[3];
  const float* w11 = (const float*)d_in[4];
  const float* w20 = (const float*)d_in[5];
  const float* w21 = (const float*)d_in[6];
  const float* w30 = (const float*)d_in[7];
  const float* w31 = (const float*)d_in[8];
  const float* sw  = (const float*)d_in[9];
  const float* wo  = (const float*)d_in[10];
  float* out = (float*)d_out;

  u16* base  = (u16*)d_ws;
  u16* qb    = base;
  u16* vb    = base + 4194304;
  u16* w1cat = base + 8388608;
  u16* w3cat = base + 8912896;
  u16* wob   = base + 9437184;
  u16* w2b0  = base + 9699328;
  u16* w2b1  = base + 9764864;
  char* fb = (char*)d_ws + 19791872;
  float* logitsC = (float*)fb;            // [8192][384]
  u16* rqcat = (u16*)(logitsC + 3145728); // [8192][1024]
  u16* vcat  = rqcat + 8388608;           // [8192][1024]
  u16* xb    = vcat + 8388608;            // [8192][512]
  // total ws use: 74,317,824 bytes

  convert_all<<<dim3(9664), dim3(256), 0, stream>>>(q, v, w10, w11, w30, w31, wo, w20, w21, base);

  dim3 blk(256);
  k_qv8<<<dim3(256), dim3(512), 0, stream>>>(qb, vb, w1cat, w3cat, rqcat, vcat);
  k_logits<<<dim3(64, 3), blk, 0, stream>>>(rqcat, w2b0, w2b1, logitsC);
  k_attn4<<<dim3(32, 4, 4), dim3(512), 0, stream>>>(logitsC, vcat, sw, xb);
  k_final<<<dim3(64, 4), blk, 0, stream>>>(xb, wob, out);
}